// Round 1
// baseline (1118.858 us; speedup 1.0000x reference)
//
#include <hip/hip_runtime.h>
#include <math.h>

#define B_ 4
#define L_ 2048
#define S_ 2048
#define H_ 8
#define E_ 64
#define TL 64
#define TS 64
#define EPS 1e-6f

// ---------------------------------------------------------------------------
// Kernel 1: fused axis-aligned transform.
// std over axis=-2 (the H axis, 8 values, ddof=1) per (b,l,e);
// xt = tanh(x * 1/(std+eps) * dw) * dp.
// One thread per (b,l,e): 8 strided loads, lane-coalesced across e.
// ---------------------------------------------------------------------------
__global__ __launch_bounds__(256) void transform_kernel(
    const float* __restrict__ x, float* __restrict__ xt,
    const float* __restrict__ dwp, const float* __restrict__ dpp)
{
    int g = blockIdx.x * 256 + threadIdx.x;      // over B*L*E = 524288
    int e = g & 63;
    int bl = g >> 6;
    if (bl >= B_ * L_) return;
    size_t base = (size_t)bl * (H_ * E_) + e;

    float v[8], s = 0.f, q = 0.f;
#pragma unroll
    for (int h = 0; h < 8; ++h) {
        float t = x[base + h * E_];
        v[h] = t; s += t; q += t * t;
    }
    float mean = s * 0.125f;
    float var  = (q - s * mean) * (1.f / 7.f);   // ddof=1, N=8
    var = fmaxf(var, 0.f);
    float inv = 1.f / (sqrtf(var) + EPS);        // (1/(std+eps))^P, P=1
    float w = dwp[0] * inv;
    float d = dpp[0];
#pragma unroll
    for (int h = 0; h < 8; ++h)
        xt[base + h * E_] = tanhf(v[h] * w) * d;
}

// ---------------------------------------------------------------------------
// Kernel 2: attention with per-row tau. Two passes over K per Q-tile:
//   pass 1: scores -> row sum/sumsq/max  (tau needs the full row)
//   pass 2: recompute scores, p = exp(alpha*(s-max)), denom += p, O += p*V
// Block: 256 threads, TL=64 q-rows for one (b,h). 4x4 register micro-tiles.
// ---------------------------------------------------------------------------
__global__ __launch_bounds__(256) void attn_kernel(
    const float* __restrict__ qt, const float* __restrict__ kt,
    const float* __restrict__ vv, float* __restrict__ out)
{
    __shared__ float qs[TL][E_ + 1];   // pad 65: <=2-way bank conflicts
    __shared__ float ks[TS][E_ + 1];
    __shared__ float vs[TS][E_];       // stride 64: aligned float4 rows
    __shared__ float Pt[TL][TS + 1];
    __shared__ float rsum[TL], rsq[TL], rmax[TL];
    __shared__ float ralpha[TL], rmaxs[TL], rden[TL];

    const int tid = threadIdx.x;
    const int l0  = blockIdx.x * TL;
    const int h   = blockIdx.y;
    const int b   = blockIdx.z;

    const int rgrp = tid >> 4;         // 0..15
    const int cgrp = tid & 15;         // 0..15
    const int r0 = rgrp * 4, c0 = cgrp * 4;

    // load q tile (64x64), coalesced float4
    for (int i = tid; i < TL * 16; i += 256) {
        int r = i >> 4, c4 = (i & 15) * 4;
        const float4 f = *(const float4*)&qt[((size_t)(b * L_ + l0 + r) * H_ + h) * E_ + c4];
        qs[r][c4 + 0] = f.x; qs[r][c4 + 1] = f.y; qs[r][c4 + 2] = f.z; qs[r][c4 + 3] = f.w;
    }
    if (tid < TL) { rsum[tid] = 0.f; rsq[tid] = 0.f; rmax[tid] = -3.0e38f; rden[tid] = 0.f; }
    __syncthreads();

    // ---------------- PASS 1: row statistics ----------------
    for (int st = 0; st < S_ / TS; ++st) {
        __syncthreads();               // prior Pt consumers done
        for (int i = tid; i < TS * 16; i += 256) {
            int r = i >> 4, c4 = (i & 15) * 4;
            const float4 f = *(const float4*)&kt[((size_t)(b * S_ + st * TS + r) * H_ + h) * E_ + c4];
            ks[r][c4 + 0] = f.x; ks[r][c4 + 1] = f.y; ks[r][c4 + 2] = f.z; ks[r][c4 + 3] = f.w;
        }
        __syncthreads();

        float acc[4][4] = {};
        for (int e = 0; e < E_; ++e) {
            float qv[4], kv[4];
#pragma unroll
            for (int i = 0; i < 4; ++i) qv[i] = qs[r0 + i][e];
#pragma unroll
            for (int j = 0; j < 4; ++j) kv[j] = ks[c0 + j][e];
#pragma unroll
            for (int i = 0; i < 4; ++i)
#pragma unroll
                for (int j = 0; j < 4; ++j) acc[i][j] += qv[i] * kv[j];
        }
#pragma unroll
        for (int i = 0; i < 4; ++i)
#pragma unroll
            for (int j = 0; j < 4; ++j) Pt[r0 + i][c0 + j] = acc[i][j];
        __syncthreads();

        if (tid < TL) {
            float s = rsum[tid], q = rsq[tid], m = rmax[tid];
            for (int c = 0; c < TS; ++c) {
                float x2 = Pt[tid][c];
                s += x2; q += x2 * x2; m = fmaxf(m, x2);
            }
            rsum[tid] = s; rsq[tid] = q; rmax[tid] = m;
        }
    }
    __syncthreads();
    if (tid < TL) {
        float s = rsum[tid];
        float var = (rsq[tid] - s * s * (1.f / S_)) * (1.f / (S_ - 1));  // ddof=1
        var = fmaxf(var, 0.f);
        float tau = sqrtf(var + EPS);
        ralpha[tid] = 0.125f / tau;    // scale = 1/sqrt(64)
        rmaxs[tid] = rmax[tid];
    }

    // ---------------- PASS 2: softmax + PV ----------------
    float oacc[4][4] = {};
    for (int st = 0; st < S_ / TS; ++st) {
        __syncthreads();               // prior Pt/vs consumers done
        for (int i = tid; i < TS * 16; i += 256) {
            int r = i >> 4, c4 = (i & 15) * 4;
            size_t base = ((size_t)(b * S_ + st * TS + r) * H_ + h) * E_ + c4;
            const float4 f = *(const float4*)&kt[base];
            ks[r][c4 + 0] = f.x; ks[r][c4 + 1] = f.y; ks[r][c4 + 2] = f.z; ks[r][c4 + 3] = f.w;
            *(float4*)&vs[r][c4] = *(const float4*)&vv[base];
        }
        __syncthreads();

        float acc[4][4] = {};
        for (int e = 0; e < E_; ++e) {
            float qv[4], kv[4];
#pragma unroll
            for (int i = 0; i < 4; ++i) qv[i] = qs[r0 + i][e];
#pragma unroll
            for (int j = 0; j < 4; ++j) kv[j] = ks[c0 + j][e];
#pragma unroll
            for (int i = 0; i < 4; ++i)
#pragma unroll
                for (int j = 0; j < 4; ++j) acc[i][j] += qv[i] * kv[j];
        }
#pragma unroll
        for (int i = 0; i < 4; ++i) {
            float al = ralpha[r0 + i], mx = rmaxs[r0 + i];
#pragma unroll
            for (int j = 0; j < 4; ++j)
                Pt[r0 + i][c0 + j] = __expf(al * (acc[i][j] - mx));
        }
        __syncthreads();

        if (tid < TL) {
            float dsum = 0.f;
            for (int c = 0; c < TS; ++c) dsum += Pt[tid][c];
            rden[tid] += dsum;
        }
        for (int s2 = 0; s2 < TS; ++s2) {
            float pv[4];
#pragma unroll
            for (int i = 0; i < 4; ++i) pv[i] = Pt[r0 + i][s2];
            const float4 vf = *(const float4*)&vs[s2][c0];
#pragma unroll
            for (int i = 0; i < 4; ++i) {
                oacc[i][0] += pv[i] * vf.x;
                oacc[i][1] += pv[i] * vf.y;
                oacc[i][2] += pv[i] * vf.z;
                oacc[i][3] += pv[i] * vf.w;
            }
        }
    }
    __syncthreads();                   // rden final

#pragma unroll
    for (int i = 0; i < 4; ++i) {
        float dn = 1.f / rden[r0 + i];
        float4 o;
        o.x = oacc[i][0] * dn; o.y = oacc[i][1] * dn;
        o.z = oacc[i][2] * dn; o.w = oacc[i][3] * dn;
        *(float4*)&out[((size_t)(b * L_ + l0 + r0 + i) * H_ + h) * E_ + c0] = o;
    }
}

extern "C" void kernel_launch(void* const* d_in, const int* in_sizes, int n_in,
                              void* d_out, int out_size, void* d_ws, size_t ws_size,
                              hipStream_t stream)
{
    const float* q  = (const float*)d_in[0];
    const float* k  = (const float*)d_in[1];
    const float* v  = (const float*)d_in[2];
    // d_in[3] = attn_mask (unused, mask_flag=False)
    const float* dw = (const float*)d_in[4];
    const float* dp = (const float*)d_in[5];
    float* out = (float*)d_out;

    float* qt = (float*)d_ws;                        // B*L*H*E floats
    float* kt = qt + (size_t)B_ * L_ * H_ * E_;      // B*S*H*E floats

    transform_kernel<<<(B_ * L_ * E_) / 256, 256, 0, stream>>>(q, qt, dw, dp);
    transform_kernel<<<(B_ * S_ * E_) / 256, 256, 0, stream>>>(k, kt, dw, dp);

    dim3 grid(L_ / TL, H_, B_);
    attn_kernel<<<grid, 256, 0, stream>>>(qt, kt, v, out);
}

// Round 2
// 209.058 us; speedup vs baseline: 5.3519x; 5.3519x over previous
//
#include <hip/hip_runtime.h>
#include <math.h>

#define B_ 4
#define L_ 2048
#define S_ 2048
#define H_ 8
#define E_ 64
#define EPS 1e-6f

typedef __attribute__((ext_vector_type(8))) short short8;
typedef __attribute__((ext_vector_type(4))) float f32x4;

__device__ __forceinline__ unsigned short f2bf(float f) {
    unsigned int u = __float_as_uint(f);
    u = (u + 0x7fffu + ((u >> 16) & 1u)) >> 16;   // RNE
    return (unsigned short)u;
}

__device__ __forceinline__ float fast_tanh(float x) {
    float e = __expf(2.0f * x);                    // tanh = 1 - 2/(e^2x+1); saturates cleanly
    return 1.0f - 2.0f / (e + 1.0f);
}

// XOR-swizzled LDS offset: rows of 128B, 16B units swizzled by row&7
// (m97-class bank pattern for both the staging writes and the b128 frag reads)
__device__ __forceinline__ int sw(int row, int byteoff) {
    return row * 128 + (((byteoff >> 4) ^ (row & 7)) << 4) + (byteoff & 15);
}

// ---------------------------------------------------------------------------
// transform: x [B,L,H,E] f32 -> xt [B,H,L,E] bf16
// std over H axis (8 vals, ddof=1), xt = tanh(x*dw/(std+eps))*dp
// ---------------------------------------------------------------------------
__global__ __launch_bounds__(256) void transform_kernel(
    const float* __restrict__ x, unsigned short* __restrict__ xt,
    const float* __restrict__ dwp, const float* __restrict__ dpp)
{
    int g = blockIdx.x * 256 + threadIdx.x;   // B*L*E
    int e = g & 63;
    int bl = g >> 6;
    int b = bl >> 11;                          // L_=2048
    int l = bl & 2047;
    size_t base = (size_t)bl * (H_ * E_) + e;

    float v[8], s = 0.f, q = 0.f;
#pragma unroll
    for (int h = 0; h < 8; ++h) {
        float t = x[base + h * E_];
        v[h] = t; s += t; q += t * t;
    }
    float mean = s * 0.125f;
    float var = (q - s * mean) * (1.f / 7.f);  // ddof=1, N=8
    var = fmaxf(var, 0.f);
    float inv = 1.f / (sqrtf(var) + EPS);
    float wsc = dwp[0] * inv;
    float d = dpp[0];
#pragma unroll
    for (int h = 0; h < 8; ++h) {
        float t = fast_tanh(v[h] * wsc) * d;
        xt[((size_t)(b * H_ + h) * L_ + l) * E_ + e] = f2bf(t);
    }
}

// ---------------------------------------------------------------------------
// vtrans: v [B,S,H,E] f32 -> vt [B,H,E,S] bf16 (LDS-tiled 64x64 transpose)
// ---------------------------------------------------------------------------
__global__ __launch_bounds__(256) void vtrans_kernel(
    const float* __restrict__ v, unsigned short* __restrict__ vt)
{
    __shared__ float ls[64][65];
    int s0 = blockIdx.x * 64;
    int h = blockIdx.y, b = blockIdx.z;
    int t = threadIdx.x;
#pragma unroll
    for (int i = 0; i < 4; ++i) {
        int idx = t + i * 256;                 // 1024 float4 units
        int r = idx >> 4, c4 = (idx & 15) * 4;
        const float4 f = *(const float4*)&v[((size_t)(b * S_ + s0 + r) * H_ + h) * E_ + c4];
        ls[r][c4] = f.x; ls[r][c4 + 1] = f.y; ls[r][c4 + 2] = f.z; ls[r][c4 + 3] = f.w;
    }
    __syncthreads();
    size_t ob = (size_t)(b * H_ + h) * E_ * S_ + s0;
#pragma unroll
    for (int i = 0; i < 16; ++i) {
        int idx = t + i * 256;                 // 4096 elems
        int e = idx >> 6, s = idx & 63;
        vt[ob + (size_t)e * S_ + s] = f2bf(ls[s][e]);
    }
}

// ---------------------------------------------------------------------------
// attention: per block = one (b,h), 128 q rows, 4 waves x 32 rows.
// pass1: QK via MFMA -> row stats (regs, butterfly). pass2: QK again,
// p=exp(al*s-al*max) -> Pt (LDS, C->A layout), PV via MFMA.
// ---------------------------------------------------------------------------
__global__ __launch_bounds__(256, 2) void attn_kernel(
    const unsigned short* __restrict__ qt,
    const unsigned short* __restrict__ kt,
    const unsigned short* __restrict__ vt,
    float* __restrict__ out)
{
    __shared__ __align__(16) char lds[32768];
    char* ksb = lds;            // 8KB : 64 s-rows x 128B (e bf16)
    char* vsb = lds + 8192;     // 8KB : 64 e-rows x 128B (s bf16)
    char* ptb = lds + 16384;    // 16KB: 128 q-rows x 128B (s bf16)

    const int tid = threadIdx.x;
    const int lane = tid & 63;
    const int w = tid >> 6;
    const int m = lane & 15;
    const int quad = lane >> 4;
    const int l0 = blockIdx.x * 128;
    const int h = blockIdx.y, b = blockIdx.z;

    const size_t bh = (size_t)b * H_ + h;
    const unsigned short* qtb = qt + bh * ((size_t)L_ * E_);
    const unsigned short* ktb = kt + bh * ((size_t)S_ * E_);
    const unsigned short* vtb = vt + bh * ((size_t)E_ * S_);

    // Q A-fragments, register-resident for the whole kernel
    short8 qf[2][2];
#pragma unroll
    for (int mi = 0; mi < 2; ++mi)
#pragma unroll
        for (int c = 0; c < 2; ++c)
            qf[mi][c] = *(const short8*)(qtb + (size_t)(l0 + w * 32 + mi * 16 + m) * E_ + c * 32 + quad * 8);

    float ssum[2][4], ssq[2][4], smax[2][4];
#pragma unroll
    for (int mi = 0; mi < 2; ++mi)
#pragma unroll
        for (int r = 0; r < 4; ++r) { ssum[mi][r] = 0.f; ssq[mi][r] = 0.f; smax[mi][r] = -3.0e38f; }

    // ---------------- pass 1: row statistics ----------------
    for (int st = 0; st < S_ / 64; ++st) {
        __syncthreads();
        {
            const unsigned short* src = ktb + st * (64 * E_);   // contiguous 8KB tile
#pragma unroll
            for (int i = 0; i < 2; ++i) {
                int u = tid + i * 256;
                int s = u >> 3, e8 = u & 7;
                *(uint4*)(ksb + sw(s, e8 * 16)) = *(const uint4*)(src + u * 8);
            }
        }
        __syncthreads();
#pragma unroll
        for (int nt = 0; nt < 4; ++nt) {
            short8 kf0 = *(const short8*)(ksb + sw(nt * 16 + m, quad * 16));
            short8 kf1 = *(const short8*)(ksb + sw(nt * 16 + m, 64 + quad * 16));
#pragma unroll
            for (int mi = 0; mi < 2; ++mi) {
                f32x4 acc = {0.f, 0.f, 0.f, 0.f};
                acc = __builtin_amdgcn_mfma_f32_16x16x32_bf16(qf[mi][0], kf0, acc, 0, 0, 0);
                acc = __builtin_amdgcn_mfma_f32_16x16x32_bf16(qf[mi][1], kf1, acc, 0, 0, 0);
#pragma unroll
                for (int r = 0; r < 4; ++r) {
                    float sc = acc[r];
                    ssum[mi][r] += sc;
                    ssq[mi][r] = fmaf(sc, sc, ssq[mi][r]);
                    smax[mi][r] = fmaxf(smax[mi][r], sc);
                }
            }
        }
    }
    // butterfly over the 16 column-lanes (C-layout col = lane&15)
#pragma unroll
    for (int mask = 1; mask < 16; mask <<= 1)
#pragma unroll
        for (int mi = 0; mi < 2; ++mi)
#pragma unroll
            for (int r = 0; r < 4; ++r) {
                ssum[mi][r] += __shfl_xor(ssum[mi][r], mask);
                ssq[mi][r] += __shfl_xor(ssq[mi][r], mask);
                smax[mi][r] = fmaxf(smax[mi][r], __shfl_xor(smax[mi][r], mask));
            }
    float al[2][4], alm[2][4];
#pragma unroll
    for (int mi = 0; mi < 2; ++mi)
#pragma unroll
        for (int r = 0; r < 4; ++r) {
            float s = ssum[mi][r];
            float var = (ssq[mi][r] - s * s * (1.f / S_)) * (1.f / (S_ - 1));  // ddof=1
            var = fmaxf(var, 0.f);
            float tau = sqrtf(var + EPS);
            float a = 0.125f / tau;                // scale = 1/sqrt(64)
            al[mi][r] = a;
            alm[mi][r] = a * smax[mi][r];
        }

    // ---------------- pass 2: softmax + PV ----------------
    float dsum[2][4] = {};
    f32x4 oacc[2][4];
#pragma unroll
    for (int mi = 0; mi < 2; ++mi)
#pragma unroll
        for (int et = 0; et < 4; ++et) oacc[mi][et] = (f32x4){0.f, 0.f, 0.f, 0.f};

    for (int st = 0; st < S_ / 64; ++st) {
        __syncthreads();
        {
            const unsigned short* src = ktb + st * (64 * E_);
#pragma unroll
            for (int i = 0; i < 2; ++i) {
                int u = tid + i * 256;
                int s = u >> 3, e8 = u & 7;
                *(uint4*)(ksb + sw(s, e8 * 16)) = *(const uint4*)(src + u * 8);
            }
            const unsigned short* vsrc = vtb + st * 64;
#pragma unroll
            for (int i = 0; i < 2; ++i) {
                int u = tid + i * 256;
                int e = u >> 3, s8 = u & 7;
                *(uint4*)(vsb + sw(e, s8 * 16)) = *(const uint4*)(vsrc + (size_t)e * S_ + s8 * 8);
            }
        }
        __syncthreads();
#pragma unroll
        for (int nt = 0; nt < 4; ++nt) {
            short8 kf0 = *(const short8*)(ksb + sw(nt * 16 + m, quad * 16));
            short8 kf1 = *(const short8*)(ksb + sw(nt * 16 + m, 64 + quad * 16));
#pragma unroll
            for (int mi = 0; mi < 2; ++mi) {
                f32x4 acc = {0.f, 0.f, 0.f, 0.f};
                acc = __builtin_amdgcn_mfma_f32_16x16x32_bf16(qf[mi][0], kf0, acc, 0, 0, 0);
                acc = __builtin_amdgcn_mfma_f32_16x16x32_bf16(qf[mi][1], kf1, acc, 0, 0, 0);
#pragma unroll
                for (int r = 0; r < 4; ++r) {
                    float p = __expf(fmaf(al[mi][r], acc[r], -alm[mi][r]));
                    dsum[mi][r] += p;
                    *(unsigned short*)(ptb + sw(w * 32 + mi * 16 + quad * 4 + r, nt * 32 + m * 2)) = f2bf(p);
                }
            }
        }
        // PV: P (A-layout) x V (B-layout); Pt is wave-private, no barrier needed
        short8 pf[2][2];
#pragma unroll
        for (int mi = 0; mi < 2; ++mi)
#pragma unroll
            for (int c = 0; c < 2; ++c)
                pf[mi][c] = *(const short8*)(ptb + sw(w * 32 + mi * 16 + m, c * 64 + quad * 16));
#pragma unroll
        for (int et = 0; et < 4; ++et) {
            short8 vf0 = *(const short8*)(vsb + sw(et * 16 + m, quad * 16));
            short8 vf1 = *(const short8*)(vsb + sw(et * 16 + m, 64 + quad * 16));
#pragma unroll
            for (int mi = 0; mi < 2; ++mi) {
                oacc[mi][et] = __builtin_amdgcn_mfma_f32_16x16x32_bf16(pf[mi][0], vf0, oacc[mi][et], 0, 0, 0);
                oacc[mi][et] = __builtin_amdgcn_mfma_f32_16x16x32_bf16(pf[mi][1], vf1, oacc[mi][et], 0, 0, 0);
            }
        }
    }

    // denominator reduce + normalized store
#pragma unroll
    for (int mask = 1; mask < 16; mask <<= 1)
#pragma unroll
        for (int mi = 0; mi < 2; ++mi)
#pragma unroll
            for (int r = 0; r < 4; ++r)
                dsum[mi][r] += __shfl_xor(dsum[mi][r], mask);

#pragma unroll
    for (int mi = 0; mi < 2; ++mi)
#pragma unroll
        for (int r = 0; r < 4; ++r) {
            float rd = 1.0f / dsum[mi][r];
            size_t row = (size_t)(b * L_ + l0 + w * 32 + mi * 16 + quad * 4 + r);
#pragma unroll
            for (int et = 0; et < 4; ++et)
                out[(row * H_ + h) * E_ + et * 16 + m] = oacc[mi][et][r] * rd;
        }
}

extern "C" void kernel_launch(void* const* d_in, const int* in_sizes, int n_in,
                              void* d_out, int out_size, void* d_ws, size_t ws_size,
                              hipStream_t stream)
{
    const float* q = (const float*)d_in[0];
    const float* k = (const float*)d_in[1];
    const float* v = (const float*)d_in[2];
    // d_in[3] = attn_mask (unused)
    const float* dw = (const float*)d_in[4];
    const float* dp = (const float*)d_in[5];
    float* out = (float*)d_out;

    unsigned short* qt = (unsigned short*)d_ws;                    // [B,H,L,E] bf16
    unsigned short* kt = qt + (size_t)B_ * H_ * L_ * E_;           // [B,H,S,E] bf16
    unsigned short* vt = kt + (size_t)B_ * H_ * S_ * E_;           // [B,H,E,S] bf16

    transform_kernel<<<(B_ * L_ * E_) / 256, 256, 0, stream>>>(q, qt, dw, dp);
    transform_kernel<<<(B_ * S_ * E_) / 256, 256, 0, stream>>>(k, kt, dw, dp);
    dim3 tg(S_ / 64, H_, B_);
    vtrans_kernel<<<tg, 256, 0, stream>>>(v, vt);
    dim3 ag(L_ / 128, H_, B_);
    attn_kernel<<<ag, 256, 0, stream>>>(qt, kt, vt, out);
}